// Round 1
// baseline (13998.901 us; speedup 1.0000x reference)
//
#include <hip/hip_runtime.h>
#include <math.h>

namespace {

constexpr int Bc = 4, Tc = 1024, Ec = 768, Hc = 12, HSc = 64, Lc = 6;
constexpr int Vc = 32000, FFc = 3072, Mc = Bc * Tc;          // M = 4096 rows
constexpr size_t SLOT = (size_t)Mc * Ec;                     // 3,145,728 floats

// ---------------- reductions ----------------
__device__ __forceinline__ float wave_sum(float v) {
#pragma unroll
  for (int off = 32; off > 0; off >>= 1) v += __shfl_xor(v, off, 64);
  return v;
}
__device__ __forceinline__ float wave_max(float v) {
#pragma unroll
  for (int off = 32; off > 0; off >>= 1) v = fmaxf(v, __shfl_xor(v, off, 64));
  return v;
}
__device__ __forceinline__ float block_sum256(float v, volatile float* red) {
  v = wave_sum(v);
  __syncthreads();
  if ((threadIdx.x & 63) == 0) red[threadIdx.x >> 6] = v;
  __syncthreads();
  return red[0] + red[1] + red[2] + red[3];
}
__device__ __forceinline__ float block_max256(float v, volatile float* red) {
  v = wave_max(v);
  __syncthreads();
  if ((threadIdx.x & 63) == 0) red[threadIdx.x >> 6] = v;
  __syncthreads();
  return fmaxf(fmaxf(red[0], red[1]), fmaxf(red[2], red[3]));
}

// ---------------- embedding ----------------
__global__ __launch_bounds__(256) void embed_k(const int* __restrict__ tokens,
                                               const float* __restrict__ emb,
                                               const float* __restrict__ pet,
                                               float* __restrict__ x) {
  int i = blockIdx.x * 256 + threadIdx.x;      // over Mc*Ec
  int m = i / Ec, e = i - m * Ec;
  int tok = tokens[m];
  x[i] = emb[(size_t)tok * Ec + e] + pet[(size_t)(m & (Tc - 1)) * Ec + e];
}

// ---------------- layernorm (one block per row, E=768) ----------------
__global__ __launch_bounds__(256) void ln_k(const float* __restrict__ in,
                                            const float* __restrict__ g,
                                            const float* __restrict__ bb,
                                            float* __restrict__ out) {
  __shared__ float red[4];
  int row = blockIdx.x, tid = threadIdx.x;
  const float* xr = in + (size_t)row * Ec;
  float v0 = xr[tid], v1 = xr[tid + 256], v2 = xr[tid + 512];
  float mean = block_sum256(v0 + v1 + v2, red) * (1.0f / 768.0f);
  float d0 = v0 - mean, d1 = v1 - mean, d2 = v2 - mean;
  float var = block_sum256(d0 * d0 + d1 * d1 + d2 * d2, red) * (1.0f / 768.0f);
  float rs = rsqrtf(var + 1e-5f);
  float* orow = out + (size_t)row * Ec;
  orow[tid]       = d0 * rs * g[tid]       + bb[tid];
  orow[tid + 256] = d1 * rs * g[tid + 256] + bb[tid + 256];
  orow[tid + 512] = d2 * rs * g[tid + 512] + bb[tid + 512];
}

// ---------------- fp32 tiled GEMM: C[M,N] (+=) A[M,K] * B[K,N] ----------------
// BMODE 0: B row-major [K,N].  BMODE 1: B is per-head wq layout [H,E,HS];
//          element (k,n) at ((n>>6)*Ec + k)*HSc + (n&63).
template <int BMODE, bool ADD, bool BIAS, bool RELU>
__global__ __launch_bounds__(256) void gemm_k(const float* __restrict__ A,
                                              const float* __restrict__ Bm,
                                              const float* __restrict__ bias,
                                              float* __restrict__ C,
                                              int M, int N, int K) {
  __shared__ float As[16][64];   // [k][m]
  __shared__ float Bs[16][64];   // [k][n]
  const int bm = blockIdx.y * 64, bn = blockIdx.x * 64;
  const int tid = threadIdx.x;
  const int tx = tid & 15, ty = tid >> 4;
  const int ar = tid >> 2, ak = (tid & 3) << 2;   // A-load: row, k-quad
  const int bk = tid >> 4, bn4 = (tid & 15) << 2; // B-load: k-row, n-quad
  float acc[4][4] = {};
  for (int k0 = 0; k0 < K; k0 += 16) {
    float4 av = *(const float4*)(A + (size_t)(bm + ar) * K + k0 + ak);
    As[ak + 0][ar] = av.x;
    As[ak + 1][ar] = av.y;
    As[ak + 2][ar] = av.z;
    As[ak + 3][ar] = av.w;
    float4 bv;
    if (BMODE == 0) {
      bv = *(const float4*)(Bm + (size_t)(k0 + bk) * N + bn + bn4);
    } else {
      int n = bn + bn4;  // 4-aligned, never crosses a 64-wide head boundary
      bv = *(const float4*)(Bm + ((size_t)(n >> 6) * Ec + (k0 + bk)) * HSc + (n & 63));
    }
    *(float4*)&Bs[bk][bn4] = bv;
    __syncthreads();
#pragma unroll
    for (int kk = 0; kk < 16; ++kk) {
      float a0 = As[kk][ty * 4 + 0], a1 = As[kk][ty * 4 + 1];
      float a2 = As[kk][ty * 4 + 2], a3 = As[kk][ty * 4 + 3];
      float b0 = Bs[kk][tx * 4 + 0], b1 = Bs[kk][tx * 4 + 1];
      float b2 = Bs[kk][tx * 4 + 2], b3 = Bs[kk][tx * 4 + 3];
      acc[0][0] += a0 * b0; acc[0][1] += a0 * b1; acc[0][2] += a0 * b2; acc[0][3] += a0 * b3;
      acc[1][0] += a1 * b0; acc[1][1] += a1 * b1; acc[1][2] += a1 * b2; acc[1][3] += a1 * b3;
      acc[2][0] += a2 * b0; acc[2][1] += a2 * b1; acc[2][2] += a2 * b2; acc[2][3] += a2 * b3;
      acc[3][0] += a3 * b0; acc[3][1] += a3 * b1; acc[3][2] += a3 * b2; acc[3][3] += a3 * b3;
    }
    __syncthreads();
  }
#pragma unroll
  for (int i = 0; i < 4; ++i) {
    int row = bm + ty * 4 + i;
#pragma unroll
    for (int j = 0; j < 4; ++j) {
      int col = bn + tx * 4 + j;
      float v = acc[i][j];
      if (BIAS) v += bias[col];
      if (RELU) v = fmaxf(v, 0.0f);
      size_t idx = (size_t)row * N + col;
      if (ADD) v += C[idx];
      C[idx] = v;
    }
  }
}

// ---------------- attention: one 64-lane wave per (b,h,t) query row ----------
// q,k,v,o all in [M, E] layout (head h occupies columns h*64..h*64+63).
__global__ __launch_bounds__(64) void attn_k(const float* __restrict__ q,
                                             const float* __restrict__ k,
                                             const float* __restrict__ v,
                                             float* __restrict__ o) {
  __shared__ float sc[Tc];
  __shared__ float qs[64];
  const int r = blockIdx.x;           // b*H*T + h*T + t
  const int t = r & (Tc - 1);
  const int bh = r >> 10;
  const int h = bh % Hc, b = bh / Hc;
  const int lane = threadIdx.x;
  const size_t rowbase = (size_t)b * Tc * Ec + (size_t)h * HSc;
  qs[lane] = q[rowbase + (size_t)t * Ec + lane];
  __syncthreads();
  float lmax = -INFINITY;
  for (int s = lane; s <= t; s += 64) {
    const float* kr = k + rowbase + (size_t)s * Ec;
    float d = 0.0f;
#pragma unroll
    for (int f = 0; f < 64; ++f) d += qs[f] * kr[f];
    d *= 0.125f;                      // HS^-0.5
    sc[s] = d;
    lmax = fmaxf(lmax, d);
  }
  lmax = wave_max(lmax);
  float lsum = 0.0f;
  for (int s = lane; s <= t; s += 64) {  // each lane rewrites its own entries
    float p = __expf(sc[s] - lmax);
    sc[s] = p;
    lsum += p;
  }
  lsum = wave_sum(lsum);
  __syncthreads();                    // publish p values to all lanes
  const float inv = 1.0f / lsum;
  float acc = 0.0f;
  for (int s = 0; s <= t; ++s) acc += sc[s] * v[rowbase + (size_t)s * Ec + lane];
  o[rowbase + (size_t)t * Ec + lane] = acc * inv;
}

// ---------------- softmax cross-entropy ----------------
__global__ __launch_bounds__(256) void loss_k(const float* __restrict__ logits,
                                              const int* __restrict__ targets,
                                              float* __restrict__ rowloss) {
  __shared__ float red[4];
  int row = blockIdx.x;
  const float* lr = logits + (size_t)row * Vc;
  float m = -INFINITY;
  for (int j = threadIdx.x; j < Vc; j += 256) m = fmaxf(m, lr[j]);
  m = block_max256(m, red);
  float s = 0.0f;
  for (int j = threadIdx.x; j < Vc; j += 256) s += __expf(lr[j] - m);
  s = block_sum256(s, red);
  if (threadIdx.x == 0) rowloss[row] = -(lr[targets[row]] - m - logf(s));
}

__global__ __launch_bounds__(1024) void lossred_k(const float* __restrict__ rowloss,
                                                  float* __restrict__ out) {
  __shared__ float red[16];
  float s = 0.0f;
  for (int i = threadIdx.x; i < Mc; i += 1024) s += rowloss[i];
  s = wave_sum(s);
  if ((threadIdx.x & 63) == 0) red[threadIdx.x >> 6] = s;
  __syncthreads();
  if (threadIdx.x == 0) {
    float tot = 0.0f;
#pragma unroll
    for (int i = 0; i < 16; ++i) tot += red[i];
    out[0] = tot * (1.0f / (float)Mc);
  }
}

}  // namespace

extern "C" void kernel_launch(void* const* d_in, const int* in_sizes, int n_in,
                              void* d_out, int out_size, void* d_ws, size_t ws_size,
                              hipStream_t stream) {
  const int*   tokens  = (const int*)d_in[0];
  const int*   targets = (const int*)d_in[1];
  const float* tok_emb = (const float*)d_in[2];
  const float* pet     = (const float*)d_in[3];
  const float* wq      = (const float*)d_in[4];
  const float* wk      = (const float*)d_in[5];
  const float* wv      = (const float*)d_in[6];
  const float* w_proj  = (const float*)d_in[7];
  const float* b_proj  = (const float*)d_in[8];
  const float* ln1_g   = (const float*)d_in[9];
  const float* ln1_b   = (const float*)d_in[10];
  const float* ln2_g   = (const float*)d_in[11];
  const float* ln2_b   = (const float*)d_in[12];
  const float* w_ff1   = (const float*)d_in[13];
  const float* b_ff1   = (const float*)d_in[14];
  const float* w_ff2   = (const float*)d_in[15];
  const float* b_ff2   = (const float*)d_in[16];
  const float* lnf_g   = (const float*)d_in[17];
  const float* lnf_b   = (const float*)d_in[18];
  const float* w_out   = (const float*)d_in[19];
  const float* b_out   = (const float*)d_in[20];

  float* out = (float*)d_out;
  // persistent scratch in d_ws (~25.2 MB)
  float* x       = (float*)d_ws;
  float* hbuf    = x + SLOT;
  float* rowloss = hbuf + SLOT;
  // transient scratch inside d_out's logits region (dead before final GEMM)
  float* fq   = out;
  float* fk   = out + SLOT;
  float* fv   = out + 2 * SLOT;
  float* fatt = out + 3 * SLOT;
  float* fffh = out;  // [M, FF] spans 4 slots; q/k/v/att dead by then

  embed_k<<<(Mc * Ec) / 256, 256, 0, stream>>>(tokens, tok_emb, pet, x);

  const dim3 g768(Ec / 64, Mc / 64);
  for (int l = 0; l < Lc; ++l) {
    ln_k<<<Mc, 256, 0, stream>>>(x, ln1_g + (size_t)l * Ec, ln1_b + (size_t)l * Ec, hbuf);
    const size_t wo = (size_t)l * Hc * Ec * HSc;
    gemm_k<1, false, false, false><<<g768, 256, 0, stream>>>(hbuf, wq + wo, nullptr, fq, Mc, Ec, Ec);
    gemm_k<1, false, false, false><<<g768, 256, 0, stream>>>(hbuf, wk + wo, nullptr, fk, Mc, Ec, Ec);
    gemm_k<1, false, false, false><<<g768, 256, 0, stream>>>(hbuf, wv + wo, nullptr, fv, Mc, Ec, Ec);
    attn_k<<<Bc * Hc * Tc, 64, 0, stream>>>(fq, fk, fv, fatt);
    gemm_k<0, true, true, false><<<g768, 256, 0, stream>>>(
        fatt, w_proj + (size_t)l * Ec * Ec, b_proj + (size_t)l * Ec, x, Mc, Ec, Ec);
    ln_k<<<Mc, 256, 0, stream>>>(x, ln2_g + (size_t)l * Ec, ln2_b + (size_t)l * Ec, hbuf);
    gemm_k<0, false, true, true><<<dim3(FFc / 64, Mc / 64), 256, 0, stream>>>(
        hbuf, w_ff1 + (size_t)l * Ec * FFc, b_ff1 + (size_t)l * FFc, fffh, Mc, FFc, Ec);
    gemm_k<0, true, true, false><<<g768, 256, 0, stream>>>(
        fffh, w_ff2 + (size_t)l * FFc * Ec, b_ff2 + (size_t)l * Ec, x, Mc, Ec, FFc);
  }
  ln_k<<<Mc, 256, 0, stream>>>(x, lnf_g, lnf_b, hbuf);
  gemm_k<0, false, true, false><<<dim3(Vc / 64, Mc / 64), 256, 0, stream>>>(
      hbuf, w_out, b_out, out, Mc, Vc, Ec);
  loss_k<<<Mc, 256, 0, stream>>>(out, targets, rowloss);
  lossred_k<<<1, 1024, 0, stream>>>(rowloss, out + (size_t)Mc * Vc);
}

// Round 2
// 5511.580 us; speedup vs baseline: 2.5399x; 2.5399x over previous
//
#include <hip/hip_runtime.h>
#include <math.h>

namespace {

constexpr int Bc = 4, Tc = 1024, Ec = 768, Hc = 12, Lc = 6;
constexpr int Vc = 32000, FFc = 3072, Mc = Bc * Tc;   // M = 4096
constexpr int QKVN = 3 * Ec;                          // 2304

typedef __bf16 bf16x8 __attribute__((ext_vector_type(8)));
typedef float f32x4 __attribute__((ext_vector_type(4)));

__device__ __forceinline__ unsigned short f2bf(float f) {
  unsigned u = __builtin_bit_cast(unsigned, f);
  u += 0x7FFFu + ((u >> 16) & 1u);
  return (unsigned short)(u >> 16);
}
__device__ __forceinline__ float ubf(unsigned short h) {
  return __builtin_bit_cast(float, (unsigned)h << 16);
}
__device__ __forceinline__ float bflo(unsigned u) {
  return __builtin_bit_cast(float, u << 16);
}
__device__ __forceinline__ float bfhi(unsigned u) {
  return __builtin_bit_cast(float, u & 0xFFFF0000u);
}

__device__ __forceinline__ float wave_sum(float v) {
#pragma unroll
  for (int off = 32; off > 0; off >>= 1) v += __shfl_xor(v, off, 64);
  return v;
}
__device__ __forceinline__ float wave_max(float v) {
#pragma unroll
  for (int off = 32; off > 0; off >>= 1) v = fmaxf(v, __shfl_xor(v, off, 64));
  return v;
}
__device__ __forceinline__ float block_sum256(float v, volatile float* red) {
  v = wave_sum(v);
  __syncthreads();
  if ((threadIdx.x & 63) == 0) red[threadIdx.x >> 6] = v;
  __syncthreads();
  return red[0] + red[1] + red[2] + red[3];
}

// ---------------- embedding ----------------
__global__ __launch_bounds__(256) void embed_k(const int* __restrict__ tokens,
                                               const float* __restrict__ emb,
                                               const float* __restrict__ pet,
                                               float* __restrict__ x) {
  int i = blockIdx.x * 256 + threadIdx.x;
  int m = i / Ec, e = i - m * Ec;
  int tok = tokens[m];
  x[i] = emb[(size_t)tok * Ec + e] + pet[(size_t)(m & (Tc - 1)) * Ec + e];
}

// ---------------- layernorm: fp32 in -> bf16 out ----------------
__global__ __launch_bounds__(256) void ln_k(const float* __restrict__ in,
                                            const float* __restrict__ g,
                                            const float* __restrict__ bb,
                                            unsigned short* __restrict__ outp) {
  __shared__ float red[4];
  int row = blockIdx.x, tid = threadIdx.x;
  const float* xr = in + (size_t)row * Ec;
  float v0 = xr[tid], v1 = xr[tid + 256], v2 = xr[tid + 512];
  float mean = block_sum256(v0 + v1 + v2, red) * (1.0f / 768.0f);
  float d0 = v0 - mean, d1 = v1 - mean, d2 = v2 - mean;
  float var = block_sum256(d0 * d0 + d1 * d1 + d2 * d2, red) * (1.0f / 768.0f);
  float rs = rsqrtf(var + 1e-5f);
  unsigned short* orow = outp + (size_t)row * Ec;
  orow[tid]       = f2bf(d0 * rs * g[tid]       + bb[tid]);
  orow[tid + 256] = f2bf(d1 * rs * g[tid + 256] + bb[tid + 256]);
  orow[tid + 512] = f2bf(d2 * rs * g[tid + 512] + bb[tid + 512]);
}

// ------- weight convert: [K][N] fp32 -> [N][K] bf16, batched -------
__global__ __launch_bounds__(256) void tcvt_k(const float* __restrict__ src,
                                              unsigned short* __restrict__ dst,
                                              int K, int N,
                                              size_t srcBatch, size_t dstBatch) {
  __shared__ float t[64][65];
  const float* s = src + blockIdx.z * srcBatch;
  unsigned short* d = dst + blockIdx.z * dstBatch;
  int k0 = blockIdx.y * 64, n0 = blockIdx.x * 64;
  int tid = threadIdx.x;
#pragma unroll
  for (int i = 0; i < 16; ++i) {
    int rr = (tid >> 6) + i * 4, cc = tid & 63;
    t[rr][cc] = s[(size_t)(k0 + rr) * N + n0 + cc];
  }
  __syncthreads();
#pragma unroll
  for (int i = 0; i < 16; ++i) {
    int rr = (tid >> 6) + i * 4, cc = tid & 63;
    d[(size_t)(n0 + rr) * K + k0 + cc] = f2bf(t[cc][rr]);
  }
}

// ------- wq/wk/wv [L][H][E][HS] fp32 -> fused qkvT [L][2304][768] bf16 -------
__global__ __launch_bounds__(256) void qcvt_k(const float* __restrict__ src,
                                              unsigned short* __restrict__ dst,
                                              int which) {
  __shared__ float t[64][65];
  const int z = blockIdx.y, l = z / Hc, h = z % Hc;
  const int k0 = blockIdx.x * 64;
  const int tid = threadIdx.x;
  const float* s = src + ((size_t)z * Ec + k0) * 64;
  unsigned short* d =
      dst + (size_t)l * QKVN * Ec + ((size_t)which * Ec + h * 64) * Ec + k0;
#pragma unroll
  for (int i = 0; i < 16; ++i) {
    int rr = (tid >> 6) + i * 4, cc = tid & 63;   // rr = k row, cc = f col
    t[rr][cc] = s[(size_t)rr * 64 + cc];
  }
  __syncthreads();
#pragma unroll
  for (int i = 0; i < 16; ++i) {
    int rr = (tid >> 6) + i * 4, cc = tid & 63;   // rr = f row, cc = k col
    d[(size_t)rr * Ec + cc] = f2bf(t[cc][rr]);
  }
}

// ---------------- MFMA bf16 GEMM: C[M,N] = A[M,K] * Bt[N,K]^T ----------------
// MODE: 0 = bf16 out; 1 = bf16 out + bias + relu; 2 = fp32 C += acc + bias;
//       3 = fp32 out + bias.
// BSRC: 0 = Bt bf16 [N][K] (global_load_lds); 1 = B fp32 [K][N] (reg-staged).
#define GLDS16(g, l)                                              \
  __builtin_amdgcn_global_load_lds(                               \
      (const __attribute__((address_space(1))) void*)(g),         \
      (__attribute__((address_space(3))) void*)(l), 16, 0, 0)

template <int MODE, int BSRC>
__global__ __launch_bounds__(256) void mgemm_k(
    const unsigned short* __restrict__ A, const void* __restrict__ Bv,
    const float* __restrict__ bias, void* __restrict__ Cv,
    int M, int N, int K) {
  __shared__ unsigned short AsU[128 * 64];
  __shared__ unsigned short BsU[128 * 64];
  const int tid = threadIdx.x, lane = tid & 63, wave = tid >> 6;
  const int bm = blockIdx.y * 128, bn = blockIdx.x * 128;
  const int wm = (wave >> 1) * 64, wn = (wave & 1) * 64;
  const int fr = lane & 15, fq = lane >> 4;
  const int lr8 = lane >> 3, lc8 = (lane & 7) * 8;
  f32x4 acc[4][4];
#pragma unroll
  for (int i = 0; i < 4; ++i)
#pragma unroll
    for (int j = 0; j < 4; ++j) acc[i][j] = (f32x4){0.f, 0.f, 0.f, 0.f};

  for (int k0 = 0; k0 < K; k0 += 64) {
    {  // stage A tile 128x64 via global_load_lds (linear LDS, 16B lanes)
      const unsigned short* g =
          A + (size_t)(bm + wave * 32 + lr8) * K + k0 + lc8;
      unsigned short* l = &AsU[(wave * 32 + lr8) * 64 + lc8];
#pragma unroll
      for (int it = 0; it < 4; ++it)
        GLDS16(g + (size_t)(it * 8) * K, l + it * 8 * 64);
    }
    if constexpr (BSRC == 0) {
      const unsigned short* Bt = (const unsigned short*)Bv;
      const unsigned short* g =
          Bt + (size_t)(bn + wave * 32 + lr8) * K + k0 + lc8;
      unsigned short* l = &BsU[(wave * 32 + lr8) * 64 + lc8];
#pragma unroll
      for (int it = 0; it < 4; ++it)
        GLDS16(g + (size_t)(it * 8) * K, l + it * 8 * 64);
    } else {
      const float* Bf = (const float*)Bv;
#pragma unroll
      for (int i = 0; i < 8; ++i) {
        int f4 = i * 256 + tid;
        int kk = f4 >> 5, c4 = (f4 & 31) * 4;
        float4 v = *(const float4*)(Bf + (size_t)(k0 + kk) * N + bn + c4);
        BsU[(c4 + 0) * 64 + kk] = f2bf(v.x);
        BsU[(c4 + 1) * 64 + kk] = f2bf(v.y);
        BsU[(c4 + 2) * 64 + kk] = f2bf(v.z);
        BsU[(c4 + 3) * 64 + kk] = f2bf(v.w);
      }
    }
    __syncthreads();  // drains vmcnt (GLDS) + lgkm (ds_write) before reads
#pragma unroll
    for (int kk = 0; kk < 2; ++kk) {
      bf16x8 af[4], bf[4];
#pragma unroll
      for (int i = 0; i < 4; ++i)
        af[i] = *(const bf16x8*)&AsU[(wm + i * 16 + fr) * 64 + kk * 32 + fq * 8];
#pragma unroll
      for (int j = 0; j < 4; ++j)
        bf[j] = *(const bf16x8*)&BsU[(wn + j * 16 + fr) * 64 + kk * 32 + fq * 8];
#pragma unroll
      for (int i = 0; i < 4; ++i)
#pragma unroll
        for (int j = 0; j < 4; ++j)
          acc[i][j] = __builtin_amdgcn_mfma_f32_16x16x32_bf16(af[i], bf[j],
                                                              acc[i][j], 0, 0, 0);
    }
    __syncthreads();  // all waves done reading before next stage
  }
  // epilogue: C frag mapping col=lane&15, row=(lane>>4)*4+reg [m89-verified]
#pragma unroll
  for (int i = 0; i < 4; ++i) {
    int row0 = bm + wm + i * 16 + fq * 4;
#pragma unroll
    for (int j = 0; j < 4; ++j) {
      int col = bn + wn + j * 16 + fr;
      float bval = 0.f;
      if constexpr (MODE != 0) bval = bias[col];
#pragma unroll
      for (int r = 0; r < 4; ++r) {
        size_t idx = (size_t)(row0 + r) * N + col;
        float v = acc[i][j][r];
        if constexpr (MODE == 0) {
          ((unsigned short*)Cv)[idx] = f2bf(v);
        } else if constexpr (MODE == 1) {
          ((unsigned short*)Cv)[idx] = f2bf(fmaxf(v + bval, 0.f));
        } else if constexpr (MODE == 2) {
          float* C = (float*)Cv;
          C[idx] = C[idx] + v + bval;
        } else {
          ((float*)Cv)[idx] = v + bval;
        }
      }
    }
  }
}

// ------- attention: one wave per (b,h,t) row; qkv fused [M][2304] bf16 -------
__global__ __launch_bounds__(64) void attn_k(const unsigned short* __restrict__ qkv,
                                             unsigned short* __restrict__ att) {
  __shared__ float sc[Tc];
  __shared__ float qs[64];
  const int r = blockIdx.x;
  const int t = r & (Tc - 1);
  const int bh = r >> 10;
  const int h = bh % Hc, b = bh / Hc;
  const int lane = threadIdx.x;
  const size_t brow = (size_t)b * Tc * QKVN;
  const unsigned short* kbase = qkv + brow + Ec + h * 64;
  const unsigned short* vbase = qkv + brow + 2 * Ec + h * 64;
  qs[lane] = ubf(qkv[brow + (size_t)t * QKVN + h * 64 + lane]);
  __syncthreads();
  float lmax = -INFINITY;
  for (int s = lane; s <= t; s += 64) {
    const uint4* kr = (const uint4*)(kbase + (size_t)s * QKVN);
    float d = 0.f;
#pragma unroll
    for (int i = 0; i < 8; ++i) {
      uint4 u = kr[i];
      d += qs[i * 8 + 0] * bflo(u.x) + qs[i * 8 + 1] * bfhi(u.x)
         + qs[i * 8 + 2] * bflo(u.y) + qs[i * 8 + 3] * bfhi(u.y)
         + qs[i * 8 + 4] * bflo(u.z) + qs[i * 8 + 5] * bfhi(u.z)
         + qs[i * 8 + 6] * bflo(u.w) + qs[i * 8 + 7] * bfhi(u.w);
    }
    d *= 0.125f;
    sc[s] = d;
    lmax = fmaxf(lmax, d);
  }
  lmax = wave_max(lmax);
  float lsum = 0.f;
  for (int s = lane; s <= t; s += 64) {
    float p = __expf(sc[s] - lmax);
    sc[s] = p;
    lsum += p;
  }
  lsum = wave_sum(lsum);
  __syncthreads();
  const float inv = 1.f / lsum;
  float a = 0.f;
  for (int s = 0; s <= t; ++s) a += sc[s] * ubf(vbase[(size_t)s * QKVN + lane]);
  att[((size_t)(b * Tc) + t) * Ec + h * 64 + lane] = f2bf(a * inv);
}

// ---------------- online-softmax cross-entropy ----------------
__global__ __launch_bounds__(256) void loss_k(const float* __restrict__ logits,
                                              const int* __restrict__ targets,
                                              float* __restrict__ rowloss) {
  __shared__ float redm[4], reds[4];
  const int row = blockIdx.x, tid = threadIdx.x;
  const float4* lr4 = (const float4*)(logits + (size_t)row * Vc);
  float m = -INFINITY, s = 0.f;
  for (int j = tid; j < Vc / 4; j += 256) {
    float4 v = lr4[j];
    float m0 = fmaxf(fmaxf(v.x, v.y), fmaxf(v.z, v.w));
    float nm = fmaxf(m, m0);
    s = s * __expf(m - nm) + __expf(v.x - nm) + __expf(v.y - nm) +
        __expf(v.z - nm) + __expf(v.w - nm);
    m = nm;
  }
#pragma unroll
  for (int off = 32; off; off >>= 1) {
    float om = __shfl_xor(m, off, 64), os = __shfl_xor(s, off, 64);
    float nm = fmaxf(m, om);
    s = s * __expf(m - nm) + os * __expf(om - nm);
    m = nm;
  }
  if ((tid & 63) == 0) { redm[tid >> 6] = m; reds[tid >> 6] = s; }
  __syncthreads();
  if (tid == 0) {
    float M2 = redm[0], S2 = reds[0];
#pragma unroll
    for (int w = 1; w < 4; ++w) {
      float om = redm[w], os = reds[w];
      float nm = fmaxf(M2, om);
      S2 = S2 * __expf(M2 - nm) + os * __expf(om - nm);
      M2 = nm;
    }
    float lt = logits[(size_t)row * Vc + targets[row]];
    rowloss[row] = -(lt - M2 - logf(S2));
  }
}

__global__ __launch_bounds__(1024) void lossred_k(const float* __restrict__ rowloss,
                                                  float* __restrict__ outp) {
  __shared__ float red[16];
  float s = 0.f;
  for (int i = threadIdx.x; i < Mc; i += 1024) s += rowloss[i];
  s = wave_sum(s);
  if ((threadIdx.x & 63) == 0) red[threadIdx.x >> 6] = s;
  __syncthreads();
  if (threadIdx.x == 0) {
    float tot = 0.f;
#pragma unroll
    for (int i = 0; i < 16; ++i) tot += red[i];
    outp[0] = tot * (1.0f / (float)Mc);
  }
}

}  // namespace

extern "C" void kernel_launch(void* const* d_in, const int* in_sizes, int n_in,
                              void* d_out, int out_size, void* d_ws, size_t ws_size,
                              hipStream_t stream) {
  const int*   tokens  = (const int*)d_in[0];
  const int*   targets = (const int*)d_in[1];
  const float* tok_emb = (const float*)d_in[2];
  const float* pet     = (const float*)d_in[3];
  const float* wq      = (const float*)d_in[4];
  const float* wk      = (const float*)d_in[5];
  const float* wv      = (const float*)d_in[6];
  const float* w_proj  = (const float*)d_in[7];
  const float* b_proj  = (const float*)d_in[8];
  const float* ln1_g   = (const float*)d_in[9];
  const float* ln1_b   = (const float*)d_in[10];
  const float* ln2_g   = (const float*)d_in[11];
  const float* ln2_b   = (const float*)d_in[12];
  const float* w_ff1   = (const float*)d_in[13];
  const float* b_ff1   = (const float*)d_in[14];
  const float* w_ff2   = (const float*)d_in[15];
  const float* b_ff2   = (const float*)d_in[16];
  const float* lnf_g   = (const float*)d_in[17];
  const float* lnf_b   = (const float*)d_in[18];
  const float* w_out   = (const float*)d_in[19];
  const float* b_out   = (const float*)d_in[20];

  float* out = (float*)d_out;
  char* ob = (char*)d_out;
  // scratch inside dead logits region of d_out (all write-before-read per call;
  // everything here is dead before the final logits GEMM writes out[])
  unsigned short* qkvA  = (unsigned short*)(ob + 0);          // [M][2304] bf16
  unsigned short* attA  = (unsigned short*)(ob + 18874368);   // [M][768]  bf16
  unsigned short* ffhA  = (unsigned short*)(ob + 25165824);   // [M][3072] bf16
  unsigned short* qkvT  = (unsigned short*)(ob + 50331648);   // [L][2304][768]
  unsigned short* projT = (unsigned short*)(ob + 71565312);   // [L][768][768]
  unsigned short* ff1T  = (unsigned short*)(ob + 78643200);   // [L][3072][768]
  unsigned short* ff2T  = (unsigned short*)(ob + 106954752);  // [L][768][3072]
  // d_ws: x fp32 | hbuf bf16 | rowloss | (woutT bf16 if it fits)
  char* wb = (char*)d_ws;
  float* x = (float*)wb;                                       // 12,582,912 B
  unsigned short* hbuf = (unsigned short*)(wb + 12582912);     //  6,291,456 B
  float* rowloss = (float*)(wb + 18874368);                    //     16,384 B
  unsigned short* woutT = (unsigned short*)(wb + 18890752);    // 49,152,000 B
  const bool wfit = ws_size >= (size_t)18890752 + 49152000;

  // ---- weight conversion (bf16, B^T layout) ----
  qcvt_k<<<dim3(12, 72), 256, 0, stream>>>(wq, qkvT, 0);
  qcvt_k<<<dim3(12, 72), 256, 0, stream>>>(wk, qkvT, 1);
  qcvt_k<<<dim3(12, 72), 256, 0, stream>>>(wv, qkvT, 2);
  tcvt_k<<<dim3(12, 12, 6), 256, 0, stream>>>(w_proj, projT, 768, 768,
                                              (size_t)589824, (size_t)589824);
  tcvt_k<<<dim3(48, 12, 6), 256, 0, stream>>>(w_ff1, ff1T, 768, 3072,
                                              (size_t)768 * 3072, (size_t)768 * 3072);
  tcvt_k<<<dim3(12, 48, 6), 256, 0, stream>>>(w_ff2, ff2T, 3072, 768,
                                              (size_t)768 * 3072, (size_t)768 * 3072);
  if (wfit)
    tcvt_k<<<dim3(500, 12, 1), 256, 0, stream>>>(w_out, woutT, 768, 32000, 0, 0);

  embed_k<<<(Mc * Ec) / 256, 256, 0, stream>>>(tokens, tok_emb, pet, x);

  for (int l = 0; l < Lc; ++l) {
    ln_k<<<Mc, 256, 0, stream>>>(x, ln1_g + (size_t)l * Ec, ln1_b + (size_t)l * Ec, hbuf);
    mgemm_k<0, 0><<<dim3(18, 32), 256, 0, stream>>>(
        hbuf, qkvT + (size_t)l * QKVN * Ec, nullptr, qkvA, Mc, QKVN, Ec);
    attn_k<<<Bc * Hc * Tc, 64, 0, stream>>>(qkvA, attA);
    mgemm_k<2, 0><<<dim3(6, 32), 256, 0, stream>>>(
        attA, projT + (size_t)l * Ec * Ec, b_proj + (size_t)l * Ec, x, Mc, Ec, Ec);
    ln_k<<<Mc, 256, 0, stream>>>(x, ln2_g + (size_t)l * Ec, ln2_b + (size_t)l * Ec, hbuf);
    mgemm_k<1, 0><<<dim3(24, 32), 256, 0, stream>>>(
        hbuf, ff1T + (size_t)l * Ec * FFc, b_ff1 + (size_t)l * FFc, ffhA, Mc, FFc, Ec);
    mgemm_k<2, 0><<<dim3(6, 32), 256, 0, stream>>>(
        ffhA, ff2T + (size_t)l * Ec * FFc, b_ff2 + (size_t)l * Ec, x, Mc, Ec, FFc);
  }
  ln_k<<<Mc, 256, 0, stream>>>(x, lnf_g, lnf_b, hbuf);
  if (wfit)
    mgemm_k<3, 0><<<dim3(250, 32), 256, 0, stream>>>(hbuf, woutT, b_out, out,
                                                     Mc, Vc, Ec);
  else
    mgemm_k<3, 1><<<dim3(250, 32), 256, 0, stream>>>(hbuf, w_out, b_out, out,
                                                     Mc, Vc, Ec);
  loss_k<<<Mc, 256, 0, stream>>>(out, targets, rowloss);
  lossred_k<<<1, 1024, 0, stream>>>(rowloss, out + (size_t)Mc * Vc);
}

// Round 3
// 2175.523 us; speedup vs baseline: 6.4347x; 2.5335x over previous
//
#include <hip/hip_runtime.h>
#include <math.h>

namespace {

constexpr int Bc = 4, Tc = 1024, Ec = 768, Hc = 12, Lc = 6;
constexpr int Vc = 32000, FFc = 3072, Mc = Bc * Tc;   // M = 4096
constexpr int QKVN = 3 * Ec;                          // 2304

typedef __bf16 bf16x8 __attribute__((ext_vector_type(8)));
typedef float f32x4 __attribute__((ext_vector_type(4)));

__device__ __forceinline__ unsigned short f2bf(float f) {
  unsigned u = __builtin_bit_cast(unsigned, f);
  u += 0x7FFFu + ((u >> 16) & 1u);
  return (unsigned short)(u >> 16);
}
__device__ __forceinline__ float ubf(unsigned short h) {
  return __builtin_bit_cast(float, (unsigned)h << 16);
}

__device__ __forceinline__ float wave_sum(float v) {
#pragma unroll
  for (int off = 32; off > 0; off >>= 1) v += __shfl_xor(v, off, 64);
  return v;
}
__device__ __forceinline__ float block_sum256(float v, volatile float* red) {
  v = wave_sum(v);
  __syncthreads();
  if ((threadIdx.x & 63) == 0) red[threadIdx.x >> 6] = v;
  __syncthreads();
  return red[0] + red[1] + red[2] + red[3];
}

// ---------------- embedding ----------------
__global__ __launch_bounds__(256) void embed_k(const int* __restrict__ tokens,
                                               const float* __restrict__ emb,
                                               const float* __restrict__ pet,
                                               float* __restrict__ x) {
  int i = blockIdx.x * 256 + threadIdx.x;
  int m = i / Ec, e = i - m * Ec;
  int tok = tokens[m];
  x[i] = emb[(size_t)tok * Ec + e] + pet[(size_t)(m & (Tc - 1)) * Ec + e];
}

// ---------------- layernorm: fp32 in -> bf16 out ----------------
__global__ __launch_bounds__(256) void ln_k(const float* __restrict__ in,
                                            const float* __restrict__ g,
                                            const float* __restrict__ bb,
                                            unsigned short* __restrict__ outp) {
  __shared__ float red[4];
  int row = blockIdx.x, tid = threadIdx.x;
  const float* xr = in + (size_t)row * Ec;
  float v0 = xr[tid], v1 = xr[tid + 256], v2 = xr[tid + 512];
  float mean = block_sum256(v0 + v1 + v2, red) * (1.0f / 768.0f);
  float d0 = v0 - mean, d1 = v1 - mean, d2 = v2 - mean;
  float var = block_sum256(d0 * d0 + d1 * d1 + d2 * d2, red) * (1.0f / 768.0f);
  float rs = rsqrtf(var + 1e-5f);
  unsigned short* orow = outp + (size_t)row * Ec;
  orow[tid]       = f2bf(d0 * rs * g[tid]       + bb[tid]);
  orow[tid + 256] = f2bf(d1 * rs * g[tid + 256] + bb[tid + 256]);
  orow[tid + 512] = f2bf(d2 * rs * g[tid + 512] + bb[tid + 512]);
}

// ------- weight convert: [K][N] fp32 -> [N][K] bf16, batched -------
__global__ __launch_bounds__(256) void tcvt_k(const float* __restrict__ src,
                                              unsigned short* __restrict__ dst,
                                              int K, int N,
                                              size_t srcBatch, size_t dstBatch) {
  __shared__ float t[64][65];
  const float* s = src + blockIdx.z * srcBatch;
  unsigned short* d = dst + blockIdx.z * dstBatch;
  int k0 = blockIdx.y * 64, n0 = blockIdx.x * 64;
  int tid = threadIdx.x;
#pragma unroll
  for (int i = 0; i < 16; ++i) {
    int rr = (tid >> 6) + i * 4, cc = tid & 63;
    t[rr][cc] = s[(size_t)(k0 + rr) * N + n0 + cc];
  }
  __syncthreads();
#pragma unroll
  for (int i = 0; i < 16; ++i) {
    int rr = (tid >> 6) + i * 4, cc = tid & 63;
    d[(size_t)(n0 + rr) * K + k0 + cc] = f2bf(t[cc][rr]);
  }
}

// ------- wq/wk/wv [L][H][E][HS] fp32 -> fused qkvT [L][2304][768] bf16 -------
__global__ __launch_bounds__(256) void qcvt_k(const float* __restrict__ src,
                                              unsigned short* __restrict__ dst,
                                              int which) {
  __shared__ float t[64][65];
  const int z = blockIdx.y, l = z / Hc, h = z % Hc;
  const int k0 = blockIdx.x * 64;
  const int tid = threadIdx.x;
  const float* s = src + ((size_t)z * Ec + k0) * 64;
  unsigned short* d =
      dst + (size_t)l * QKVN * Ec + ((size_t)which * Ec + h * 64) * Ec + k0;
#pragma unroll
  for (int i = 0; i < 16; ++i) {
    int rr = (tid >> 6) + i * 4, cc = tid & 63;
    t[rr][cc] = s[(size_t)rr * 64 + cc];
  }
  __syncthreads();
#pragma unroll
  for (int i = 0; i < 16; ++i) {
    int rr = (tid >> 6) + i * 4, cc = tid & 63;
    d[(size_t)rr * Ec + cc] = f2bf(t[cc][rr]);
  }
}

// ---------------- MFMA bf16 GEMM: C[M,N] = A[M,K] * Bt[N,K]^T ----------------
#define GLDS16(g, l)                                              \
  __builtin_amdgcn_global_load_lds(                               \
      (const __attribute__((address_space(1))) void*)(g),         \
      (__attribute__((address_space(3))) void*)(l), 16, 0, 0)

template <int MODE, int BSRC>
__global__ __launch_bounds__(256) void mgemm_k(
    const unsigned short* __restrict__ A, const void* __restrict__ Bv,
    const float* __restrict__ bias, void* __restrict__ Cv,
    int M, int N, int K) {
  __shared__ unsigned short AsU[128 * 64];
  __shared__ unsigned short BsU[128 * 64];
  const int tid = threadIdx.x, lane = tid & 63, wave = tid >> 6;
  const int bm = blockIdx.y * 128, bn = blockIdx.x * 128;
  const int wm = (wave >> 1) * 64, wn = (wave & 1) * 64;
  const int fr = lane & 15, fq = lane >> 4;
  const int lr8 = lane >> 3, lc8 = (lane & 7) * 8;
  f32x4 acc[4][4];
#pragma unroll
  for (int i = 0; i < 4; ++i)
#pragma unroll
    for (int j = 0; j < 4; ++j) acc[i][j] = (f32x4){0.f, 0.f, 0.f, 0.f};

  for (int k0 = 0; k0 < K; k0 += 64) {
    {
      const unsigned short* g =
          A + (size_t)(bm + wave * 32 + lr8) * K + k0 + lc8;
      unsigned short* l = &AsU[(wave * 32 + lr8) * 64 + lc8];
#pragma unroll
      for (int it = 0; it < 4; ++it)
        GLDS16(g + (size_t)(it * 8) * K, l + it * 8 * 64);
    }
    if constexpr (BSRC == 0) {
      const unsigned short* Bt = (const unsigned short*)Bv;
      const unsigned short* g =
          Bt + (size_t)(bn + wave * 32 + lr8) * K + k0 + lc8;
      unsigned short* l = &BsU[(wave * 32 + lr8) * 64 + lc8];
#pragma unroll
      for (int it = 0; it < 4; ++it)
        GLDS16(g + (size_t)(it * 8) * K, l + it * 8 * 64);
    } else {
      const float* Bf = (const float*)Bv;
#pragma unroll
      for (int i = 0; i < 8; ++i) {
        int f4 = i * 256 + tid;
        int kk = f4 >> 5, c4 = (f4 & 31) * 4;
        float4 v = *(const float4*)(Bf + (size_t)(k0 + kk) * N + bn + c4);
        BsU[(c4 + 0) * 64 + kk] = f2bf(v.x);
        BsU[(c4 + 1) * 64 + kk] = f2bf(v.y);
        BsU[(c4 + 2) * 64 + kk] = f2bf(v.z);
        BsU[(c4 + 3) * 64 + kk] = f2bf(v.w);
      }
    }
    __syncthreads();
#pragma unroll
    for (int kk = 0; kk < 2; ++kk) {
      bf16x8 af[4], bfr[4];
#pragma unroll
      for (int i = 0; i < 4; ++i)
        af[i] = *(const bf16x8*)&AsU[(wm + i * 16 + fr) * 64 + kk * 32 + fq * 8];
#pragma unroll
      for (int j = 0; j < 4; ++j)
        bfr[j] = *(const bf16x8*)&BsU[(wn + j * 16 + fr) * 64 + kk * 32 + fq * 8];
#pragma unroll
      for (int i = 0; i < 4; ++i)
#pragma unroll
        for (int j = 0; j < 4; ++j)
          acc[i][j] = __builtin_amdgcn_mfma_f32_16x16x32_bf16(af[i], bfr[j],
                                                              acc[i][j], 0, 0, 0);
    }
    __syncthreads();
  }
#pragma unroll
  for (int i = 0; i < 4; ++i) {
    int row0 = bm + wm + i * 16 + fq * 4;
#pragma unroll
    for (int j = 0; j < 4; ++j) {
      int col = bn + wn + j * 16 + fr;
      float bval = 0.f;
      if constexpr (MODE != 0) bval = bias[col];
#pragma unroll
      for (int r = 0; r < 4; ++r) {
        size_t idx = (size_t)(row0 + r) * N + col;
        float v = acc[i][j][r];
        if constexpr (MODE == 0) {
          ((unsigned short*)Cv)[idx] = f2bf(v);
        } else if constexpr (MODE == 1) {
          ((unsigned short*)Cv)[idx] = f2bf(fmaxf(v + bval, 0.f));
        } else if constexpr (MODE == 2) {
          float* C = (float*)Cv;
          C[idx] = C[idx] + v + bval;
        } else {
          ((float*)Cv)[idx] = v + bval;
        }
      }
    }
  }
}

// ------------- MFMA flash attention -------------
// Block: one (b,h), 64 query rows; 4 waves x 16 q-rows. K-tiles of 64.
// K staged [64][64] bf16 XOR-swizzled; V staged transposed Vt[hs][s] swizzled.
__global__ __launch_bounds__(256) void fattn_k(const unsigned short* __restrict__ qkv,
                                               unsigned short* __restrict__ att) {
  __shared__ unsigned short Ks[64 * 64];
  __shared__ unsigned short Vt[64 * 64];
  __shared__ unsigned short Pb[4][16 * 72];
  const int bh = blockIdx.y;
  const int b = bh / Hc, h = bh % Hc;
  const int qb = gridDim.x - 1 - blockIdx.x;   // heavy blocks dispatched first
  const int q0 = qb * 64;
  const int tid = threadIdx.x, lane = tid & 63, w = tid >> 6;
  const int fr = lane & 15, fq = lane >> 4;
  const size_t base = (size_t)b * Tc * QKVN + h * 64;

  // Q fragments (A-operand): row = q0 + w*16 + fr, k = ss*32 + fq*8 + j
  bf16x8 aq[2];
  {
    const unsigned short* qp =
        qkv + base + (size_t)(q0 + w * 16 + fr) * QKVN + fq * 8;
    aq[0] = *(const bf16x8*)qp;
    aq[1] = *(const bf16x8*)(qp + 32);
  }
  f32x4 o[4];
  float m_run[4], l_run[4];
#pragma unroll
  for (int n = 0; n < 4; ++n) o[n] = (f32x4){0.f, 0.f, 0.f, 0.f};
#pragma unroll
  for (int r = 0; r < 4; ++r) { m_run[r] = -INFINITY; l_run[r] = 0.f; }

  const int nt = qb + 1;
  for (int it = 0; it < nt; ++it) {
    const int s0 = it * 64;
    __syncthreads();   // all waves done reading previous K/V tile
    {  // stage K rows [64][64], swizzle byte ^= (row&7)<<4 on 16B units
      const int r0 = tid >> 3, c0 = (tid & 7) * 8;
      const unsigned short* kg =
          qkv + base + Ec + (size_t)(s0 + r0) * QKVN + c0;
      uint4 k0v = *(const uint4*)kg;
      uint4 k1v = *(const uint4*)(kg + (size_t)32 * QKVN);
      *(uint4*)((char*)Ks + (r0 * 128 + ((c0 * 2) ^ ((r0 & 7) << 4)))) = k0v;
      const int r1 = r0 + 32;
      *(uint4*)((char*)Ks + (r1 * 128 + ((c0 * 2) ^ ((r1 & 7) << 4)))) = k1v;
    }
    {  // stage V transposed: Vt[hs][s] = V[s][hs], packed u32 (s pairs)
      const int s2 = (tid & 31) * 2, c0v = (tid >> 5) * 8;
      const unsigned short* vg =
          qkv + base + 2 * Ec + (size_t)(s0 + s2) * QKVN + c0v;
      uint4 v0 = *(const uint4*)vg;
      uint4 v1 = *(const uint4*)(vg + QKVN);
      const unsigned short* p0 = (const unsigned short*)&v0;
      const unsigned short* p1 = (const unsigned short*)&v1;
#pragma unroll
      for (int j = 0; j < 8; ++j) {
        int hs = c0v + j;
        unsigned pk = (unsigned)p0[j] | ((unsigned)p1[j] << 16);
        *(unsigned*)((char*)Vt + (hs * 128 + ((s2 * 2) ^ ((hs & 7) << 4)))) = pk;
      }
    }
    __syncthreads();   // tile ready

    // ---- QK^T: S[q 16][s 64] per wave ----
    f32x4 s[4];
#pragma unroll
    for (int n = 0; n < 4; ++n) s[n] = (f32x4){0.f, 0.f, 0.f, 0.f};
#pragma unroll
    for (int ss = 0; ss < 2; ++ss)
#pragma unroll
      for (int n = 0; n < 4; ++n) {
        int row = n * 16 + fr;
        bf16x8 kb = *(const bf16x8*)(
            (char*)Ks + (row * 128 + ((ss * 64 + fq * 16) ^ ((row & 7) << 4))));
        s[n] = __builtin_amdgcn_mfma_f32_16x16x32_bf16(aq[ss], kb, s[n], 0, 0, 0);
      }

    // ---- scale + causal mask ----
    const bool need_mask = (s0 + 63 > q0 + w * 16);
#pragma unroll
    for (int n = 0; n < 4; ++n) {
      int scol = s0 + n * 16 + fr;
#pragma unroll
      for (int r = 0; r < 4; ++r) {
        float v = s[n][r] * 0.125f;
        if (need_mask && scol > q0 + w * 16 + fq * 4 + r) v = -INFINITY;
        s[n][r] = v;
      }
    }
    // ---- online softmax (rows live in (fq, r); cols across fr lanes) ----
    float mt[4];
#pragma unroll
    for (int r = 0; r < 4; ++r)
      mt[r] = fmaxf(fmaxf(s[0][r], s[1][r]), fmaxf(s[2][r], s[3][r]));
#pragma unroll
    for (int off = 1; off <= 8; off <<= 1)
#pragma unroll
      for (int r = 0; r < 4; ++r) mt[r] = fmaxf(mt[r], __shfl_xor(mt[r], off, 64));
    float alpha[4], rs[4];
#pragma unroll
    for (int r = 0; r < 4; ++r) {
      float mn = fmaxf(m_run[r], mt[r]);
      alpha[r] = __expf(m_run[r] - mn);
      m_run[r] = mn;
      rs[r] = 0.f;
    }
#pragma unroll
    for (int n = 0; n < 4; ++n)
#pragma unroll
      for (int r = 0; r < 4; ++r) {
        float p = __expf(s[n][r] - m_run[r]);
        s[n][r] = p;
        rs[r] += p;
      }
#pragma unroll
    for (int off = 1; off <= 8; off <<= 1)
#pragma unroll
      for (int r = 0; r < 4; ++r) rs[r] += __shfl_xor(rs[r], off, 64);
#pragma unroll
    for (int r = 0; r < 4; ++r) l_run[r] = l_run[r] * alpha[r] + rs[r];
#pragma unroll
    for (int n = 0; n < 4; ++n)
#pragma unroll
      for (int r = 0; r < 4; ++r) o[n][r] *= alpha[r];

    // ---- P -> A-operand layout via per-wave LDS (stride 72) ----
#pragma unroll
    for (int n = 0; n < 4; ++n)
#pragma unroll
      for (int r = 0; r < 4; ++r)
        Pb[w][(fq * 4 + r) * 72 + n * 16 + fr] = f2bf(s[n][r]);
    // wave-internal: compiler inserts lgkmcnt waits (same-wave in-order)
#pragma unroll
    for (int ss = 0; ss < 2; ++ss) {
      bf16x8 pa = *(const bf16x8*)&Pb[w][fr * 72 + ss * 32 + fq * 8];
#pragma unroll
      for (int n = 0; n < 4; ++n) {
        int row = n * 16 + fr;
        bf16x8 vb = *(const bf16x8*)(
            (char*)Vt + (row * 128 + ((ss * 64 + fq * 16) ^ ((row & 7) << 4))));
        o[n] = __builtin_amdgcn_mfma_f32_16x16x32_bf16(pa, vb, o[n], 0, 0, 0);
      }
    }
  }
  // ---- epilogue: O / l, write bf16 ----
#pragma unroll
  for (int r = 0; r < 4; ++r) {
    const float inv = 1.0f / l_run[r];
    const int qrow = q0 + w * 16 + fq * 4 + r;
    unsigned short* orow = att + ((size_t)(b * Tc + qrow)) * Ec + h * 64;
#pragma unroll
    for (int n = 0; n < 4; ++n) orow[n * 16 + fr] = f2bf(o[n][r] * inv);
  }
}

// ---------------- online-softmax cross-entropy ----------------
__global__ __launch_bounds__(256) void loss_k(const float* __restrict__ logits,
                                              const int* __restrict__ targets,
                                              float* __restrict__ rowloss) {
  __shared__ float redm[4], reds[4];
  const int row = blockIdx.x, tid = threadIdx.x;
  const float4* lr4 = (const float4*)(logits + (size_t)row * Vc);
  float m = -INFINITY, s = 0.f;
  for (int j = tid; j < Vc / 4; j += 256) {
    float4 v = lr4[j];
    float m0 = fmaxf(fmaxf(v.x, v.y), fmaxf(v.z, v.w));
    float nm = fmaxf(m, m0);
    s = s * __expf(m - nm) + __expf(v.x - nm) + __expf(v.y - nm) +
        __expf(v.z - nm) + __expf(v.w - nm);
    m = nm;
  }
#pragma unroll
  for (int off = 32; off; off >>= 1) {
    float om = __shfl_xor(m, off, 64), os = __shfl_xor(s, off, 64);
    float nm = fmaxf(m, om);
    s = s * __expf(m - nm) + os * __expf(om - nm);
    m = nm;
  }
  if ((tid & 63) == 0) { redm[tid >> 6] = m; reds[tid >> 6] = s; }
  __syncthreads();
  if (tid == 0) {
    float M2 = redm[0], S2 = reds[0];
#pragma unroll
    for (int w = 1; w < 4; ++w) {
      float om = redm[w], os = reds[w];
      float nm = fmaxf(M2, om);
      S2 = S2 * __expf(M2 - nm) + os * __expf(om - nm);
      M2 = nm;
    }
    float lt = logits[(size_t)row * Vc + targets[row]];
    rowloss[row] = -(lt - M2 - logf(S2));
  }
}

__global__ __launch_bounds__(1024) void lossred_k(const float* __restrict__ rowloss,
                                                  float* __restrict__ outp) {
  __shared__ float red[16];
  float s = 0.f;
  for (int i = threadIdx.x; i < Mc; i += 1024) s += rowloss[i];
  s = wave_sum(s);
  if ((threadIdx.x & 63) == 0) red[threadIdx.x >> 6] = s;
  __syncthreads();
  if (threadIdx.x == 0) {
    float tot = 0.f;
#pragma unroll
    for (int i = 0; i < 16; ++i) tot += red[i];
    outp[0] = tot * (1.0f / (float)Mc);
  }
}

}  // namespace

extern "C" void kernel_launch(void* const* d_in, const int* in_sizes, int n_in,
                              void* d_out, int out_size, void* d_ws, size_t ws_size,
                              hipStream_t stream) {
  const int*   tokens  = (const int*)d_in[0];
  const int*   targets = (const int*)d_in[1];
  const float* tok_emb = (const float*)d_in[2];
  const float* pet     = (const float*)d_in[3];
  const float* wq      = (const float*)d_in[4];
  const float* wk      = (const float*)d_in[5];
  const float* wv      = (const float*)d_in[6];
  const float* w_proj  = (const float*)d_in[7];
  const float* b_proj  = (const float*)d_in[8];
  const float* ln1_g   = (const float*)d_in[9];
  const float* ln1_b   = (const float*)d_in[10];
  const float* ln2_g   = (const float*)d_in[11];
  const float* ln2_b   = (const float*)d_in[12];
  const float* w_ff1   = (const float*)d_in[13];
  const float* b_ff1   = (const float*)d_in[14];
  const float* w_ff2   = (const float*)d_in[15];
  const float* b_ff2   = (const float*)d_in[16];
  const float* lnf_g   = (const float*)d_in[17];
  const float* lnf_b   = (const float*)d_in[18];
  const float* w_out   = (const float*)d_in[19];
  const float* b_out   = (const float*)d_in[20];

  float* out = (float*)d_out;
  char* ob = (char*)d_out;
  // scratch inside dead logits region of d_out (write-before-read per call)
  unsigned short* qkvA  = (unsigned short*)(ob + 0);          // [M][2304] bf16
  unsigned short* attA  = (unsigned short*)(ob + 18874368);   // [M][768]  bf16
  unsigned short* ffhA  = (unsigned short*)(ob + 25165824);   // [M][3072] bf16
  unsigned short* qkvT  = (unsigned short*)(ob + 50331648);   // [L][2304][768]
  unsigned short* projT = (unsigned short*)(ob + 71565312);   // [L][768][768]
  unsigned short* ff1T  = (unsigned short*)(ob + 78643200);   // [L][3072][768]
  unsigned short* ff2T  = (unsigned short*)(ob + 106954752);  // [L][768][3072]
  char* wb = (char*)d_ws;
  float* x = (float*)wb;
  unsigned short* hbuf = (unsigned short*)(wb + 12582912);
  float* rowloss = (float*)(wb + 18874368);
  unsigned short* woutT = (unsigned short*)(wb + 18890752);
  const bool wfit = ws_size >= (size_t)18890752 + 49152000;

  qcvt_k<<<dim3(12, 72), 256, 0, stream>>>(wq, qkvT, 0);
  qcvt_k<<<dim3(12, 72), 256, 0, stream>>>(wk, qkvT, 1);
  qcvt_k<<<dim3(12, 72), 256, 0, stream>>>(wv, qkvT, 2);
  tcvt_k<<<dim3(12, 12, 6), 256, 0, stream>>>(w_proj, projT, 768, 768,
                                              (size_t)589824, (size_t)589824);
  tcvt_k<<<dim3(48, 12, 6), 256, 0, stream>>>(w_ff1, ff1T, 768, 3072,
                                              (size_t)768 * 3072, (size_t)768 * 3072);
  tcvt_k<<<dim3(12, 48, 6), 256, 0, stream>>>(w_ff2, ff2T, 3072, 768,
                                              (size_t)768 * 3072, (size_t)768 * 3072);
  if (wfit)
    tcvt_k<<<dim3(500, 12, 1), 256, 0, stream>>>(w_out, woutT, 768, 32000, 0, 0);

  embed_k<<<(Mc * Ec) / 256, 256, 0, stream>>>(tokens, tok_emb, pet, x);

  for (int l = 0; l < Lc; ++l) {
    ln_k<<<Mc, 256, 0, stream>>>(x, ln1_g + (size_t)l * Ec, ln1_b + (size_t)l * Ec, hbuf);
    mgemm_k<0, 0><<<dim3(18, 32), 256, 0, stream>>>(
        hbuf, qkvT + (size_t)l * QKVN * Ec, nullptr, qkvA, Mc, QKVN, Ec);
    fattn_k<<<dim3(Tc / 64, Bc * Hc), 256, 0, stream>>>(qkvA, attA);
    mgemm_k<2, 0><<<dim3(6, 32), 256, 0, stream>>>(
        attA, projT + (size_t)l * Ec * Ec, b_proj + (size_t)l * Ec, x, Mc, Ec, Ec);
    ln_k<<<Mc, 256, 0, stream>>>(x, ln2_g + (size_t)l * Ec, ln2_b + (size_t)l * Ec, hbuf);
    mgemm_k<1, 0><<<dim3(24, 32), 256, 0, stream>>>(
        hbuf, ff1T + (size_t)l * Ec * FFc, b_ff1 + (size_t)l * FFc, ffhA, Mc, FFc, Ec);
    mgemm_k<2, 0><<<dim3(6, 32), 256, 0, stream>>>(
        ffhA, ff2T + (size_t)l * Ec * FFc, b_ff2 + (size_t)l * Ec, x, Mc, Ec, FFc);
  }
  ln_k<<<Mc, 256, 0, stream>>>(x, lnf_g, lnf_b, hbuf);
  if (wfit)
    mgemm_k<3, 0><<<dim3(250, 32), 256, 0, stream>>>(hbuf, woutT, b_out, out,
                                                     Mc, Vc, Ec);
  else
    mgemm_k<3, 1><<<dim3(250, 32), 256, 0, stream>>>(hbuf, w_out, b_out, out,
                                                     Mc, Vc, Ec);
  loss_k<<<Mc, 256, 0, stream>>>(out, targets, rowloss);
  lossred_k<<<1, 1024, 0, stream>>>(rowloss, out + (size_t)Mc * Vc);
}